// Round 7
// baseline (767.349 us; speedup 1.0000x reference)
//
#include <hip/hip_runtime.h>
#include <hip/hip_bf16.h>
#include <math.h>

#define D    256
#define BT   128     // chunk length == M tile
#define BN   64      // N tile per block (4 N-slices)
#define NSEG 32      // BT/4 segments per chunk (GEMM epilogue)

typedef unsigned short u16;
typedef unsigned int   u32;
typedef __attribute__((ext_vector_type(8))) short short8;   // 8 bf16 = 4 VGPRs
typedef __attribute__((ext_vector_type(4))) float floatx4;  // MFMA C/D frag

__device__ __forceinline__ float b2f(u16 v) {
    union { unsigned u; float f; } x; x.u = ((unsigned)v) << 16; return x.f;
}
__device__ __forceinline__ u16 f2b(float f) {
    union { unsigned u; float f; } x; x.f = f;
    unsigned lsb = (x.u >> 16) & 1;
    x.u += 0x7fffu + lsb;                 // RNE
    return (u16)(x.u >> 16);
}
__device__ __forceinline__ float sigm(float x) {
    return __builtin_amdgcn_rcpf(1.0f + __expf(-x));
}
__device__ __forceinline__ float tanhfast(float x) {
    return 1.0f - 2.0f * __builtin_amdgcn_rcpf(__expf(2.0f * x) + 1.0f);
}
__device__ __forceinline__ void async16(const u16* g, u16* l) {
    __builtin_amdgcn_global_load_lds(
        (const __attribute__((address_space(1))) unsigned int*)g,
        (__attribute__((address_space(3))) unsigned int*)l, 16, 0, 0);
}

// ---------------------------------------------------------------------------
// weight transpose + bf16 cast: wt[combo][m][n][k] = bf16(W[k][n])
// combo 0..2 = fwd layer l; 3..4 = bwd layer (l<2). m: 0=Wz, 1=Whx, 2=Whq.
// ---------------------------------------------------------------------------
__global__ __launch_bounds__(256) void wtrans_kernel(
    const float* __restrict__ Wz_f, const float* __restrict__ Wh_f,
    const float* __restrict__ Wz_b, const float* __restrict__ Wh_b,
    u16* __restrict__ wt)
{
    int id = blockIdx.x * 256 + threadIdx.x;       // < 5*3*65536
    int combo = id / (3 * 65536);
    int rem   = id % (3 * 65536);
    int m = rem >> 16;
    int e = rem & 65535;
    int k = e >> 8, n = e & 255;
    int l   = combo < 3 ? combo : combo - 3;
    int dir = combo < 3 ? 0 : 1;
    float v;
    if (m == 0) {
        const float* Wz = dir ? Wz_b : Wz_f;
        v = Wz[((size_t)l * D + k) * D + n];
    } else {
        const float* Wh = dir ? Wh_b : Wh_f;
        int kk = (m == 2) ? (k + D) : k;
        v = Wh[((size_t)l * 2 * D + kk) * D + n];
    }
    wt[(size_t)combo * 3 * 65536 + (size_t)m * 65536 + (size_t)n * D + k] = f2b(v);
}

// ---------------------------------------------------------------------------
// prep: xb = bf16(x), q broadcast, xq = bf16(x*qbf)
// ---------------------------------------------------------------------------
__global__ __launch_bounds__(256) void prep0_kernel(
    const float* __restrict__ story, const float* __restrict__ question,
    u16* __restrict__ xb, u16* __restrict__ q, u16* __restrict__ xq)
{
    long id = (long)blockIdx.x * 256 + threadIdx.x;
    long row = id >> 5;
    int  d0  = (int)(id & 31) * 8;
    const float* xp = story + row * D + d0;
    float4 xa = *(const float4*)xp;
    float4 xc = *(const float4*)(xp + 4);
    float xv[8] = {xa.x, xa.y, xa.z, xa.w, xc.x, xc.y, xc.z, xc.w};
    short8 xs, qs, xqs;
    #pragma unroll
    for (int i = 0; i < 8; ++i) {
        u16 qb = f2b(question[d0 + i]);
        xs[i]  = (short)f2b(xv[i]);
        qs[i]  = (short)qb;
        xqs[i] = (short)f2b(xv[i] * b2f(qb));
    }
    long o = id * 8;
    *(short8*)(xb + o) = xs;
    *(short8*)(q  + o) = qs;
    *(short8*)(xq + o) = xqs;
}

// ---------------------------------------------------------------------------
// LDS stage layouts
// ---------------------------------------------------------------------------
struct StageS {      // single-direction (3 B streams)
    u16 ax [BT * 32]; u16 aq [BT * 32]; u16 axq[BT * 32];   // 8KB each
    u16 bz_[BN * 32]; u16 bx_[BN * 32]; u16 bq_[BN * 32];   // 4KB each
};
struct StageF {      // fused (6 B streams)
    u16 ax [BT * 32]; u16 aq [BT * 32]; u16 axq[BT * 32];
    u16 bzf_[BN * 32]; u16 bxf_[BN * 32]; u16 bqf_[BN * 32];
    u16 bzb_[BN * 32]; u16 bxb_[BN * 32]; u16 bqb_[BN * 32];
};
struct EpiP { float segA[NSEG][BN]; float segB[NSEG][BN]; };
struct EpiF {
    float segAf[NSEG][BN]; float segBf[NSEG][BN];
    float segAb[NSEG][BN]; float segBb[NSEG][BN];
};
union SharedP { StageS st; EpiP ep; };
union SharedF { StageF st; EpiF ep; };

// ===========================================================================
// Single-direction GEMM (layer 2 fwd + planP): gates -> chunk agg
// (+ optional packed a,b writeout).
// ===========================================================================
template<int FWD, int ABOUT>
__global__ __launch_bounds__(256) void qrn_g5(
    const u16* __restrict__ xbg, const u16* __restrict__ qg,
    const u16* __restrict__ xqg, const u16* __restrict__ wt,
    const float* __restrict__ bz, const float* __restrict__ bh,
    float* __restrict__ aggA, float* __restrict__ aggB,
    u32* __restrict__ abg)
{
    __shared__ SharedP sh;
    const int tid  = threadIdx.x;
    const int gidx = ((int)blockIdx.x & 7) * 256 + ((int)blockIdx.x >> 3);
    const int c    = gidx >> 2;
    const int n0   = (gidx & 3) * BN;
    const int t0   = c * BT;
    const int lane = tid & 63, w = tid >> 6;
    const int lr   = lane & 15, quad = lane >> 4;

    int offA[2], offB[4];
    #pragma unroll
    for (int rt = 0; rt < 2; ++rt) {
        int row = w * 32 + rt * 16 + lr;
        offA[rt] = row * 32 + (quad ^ ((row >> 1) & 3)) * 8;
    }
    #pragma unroll
    for (int ct = 0; ct < 4; ++ct) {
        int n = ct * 16 + lr;
        offB[ct] = n * 32 + (quad ^ ((n >> 1) & 3)) * 8;
    }

    floatx4 accz[2][4], acch[2][4];
    #pragma unroll
    for (int rt = 0; rt < 2; ++rt)
        #pragma unroll
        for (int ct = 0; ct < 4; ++ct) {
            accz[rt][ct] = (floatx4){0.f,0.f,0.f,0.f};
            acch[rt][ct] = (floatx4){0.f,0.f,0.f,0.f};
        }

    const u16* wz = wt;
    const u16* wx = wt + 65536;
    const u16* wq = wt + 131072;
    const int wbase = (tid & ~63) * 8;

    for (int k0 = 0; k0 < D; k0 += 32) {
        #pragma unroll
        for (int i = 0; i < 2; ++i) {
            int u = i * 256 + tid;
            int row = u >> 2, sl = u & 3;
            int gg = sl ^ ((row >> 1) & 3);
            size_t go = (size_t)(t0 + row) * D + k0 + gg * 8;
            int lb = (i * 256 + (tid & ~63)) * 8;
            async16(xbg + go, sh.st.ax  + lb);
            async16(qg  + go, sh.st.aq  + lb);
            async16(xqg + go, sh.st.axq + lb);
        }
        {
            int n = tid >> 2, sl = tid & 3;
            int gg = sl ^ ((n >> 1) & 3);
            size_t go = (size_t)(n0 + n) * D + k0 + gg * 8;
            async16(wz + go, sh.st.bz_ + wbase);
            async16(wx + go, sh.st.bx_ + wbase);
            async16(wq + go, sh.st.bq_ + wbase);
        }
        __syncthreads();

        short8 fx[2], fq[2], fxq[2];
        #pragma unroll
        for (int rt = 0; rt < 2; ++rt) {
            fx [rt] = *(const short8*)(sh.st.ax  + offA[rt]);
            fq [rt] = *(const short8*)(sh.st.aq  + offA[rt]);
            fxq[rt] = *(const short8*)(sh.st.axq + offA[rt]);
        }
        #pragma unroll
        for (int ct = 0; ct < 4; ++ct) {
            short8 vz = *(const short8*)(sh.st.bz_ + offB[ct]);
            short8 vx = *(const short8*)(sh.st.bx_ + offB[ct]);
            short8 vq = *(const short8*)(sh.st.bq_ + offB[ct]);
            #pragma unroll
            for (int rt = 0; rt < 2; ++rt) {
                accz[rt][ct] = __builtin_amdgcn_mfma_f32_16x16x32_bf16(fxq[rt], vz, accz[rt][ct], 0, 0, 0);
                acch[rt][ct] = __builtin_amdgcn_mfma_f32_16x16x32_bf16(fx [rt], vx, acch[rt][ct], 0, 0, 0);
                acch[rt][ct] = __builtin_amdgcn_mfma_f32_16x16x32_bf16(fq [rt], vq, acch[rt][ct], 0, 0, 0);
            }
        }
        __syncthreads();
    }

    float av[2][4][4], bv[2][4][4];
    #pragma unroll
    for (int ct = 0; ct < 4; ++ct) {
        int n = n0 + ct * 16 + lr;
        float bzn = bz[n], bhn = bh[n];
        #pragma unroll
        for (int rt = 0; rt < 2; ++rt)
            #pragma unroll
            for (int r = 0; r < 4; ++r) {
                float z  = sigm(accz[rt][ct][r] + bzn);
                float ht = tanhfast(acch[rt][ct][r] + bhn);
                av[rt][ct][r] = 1.0f - z;
                bv[rt][ct][r] = z * ht;
            }
    }
    #pragma unroll
    for (int rt = 0; rt < 2; ++rt)
        #pragma unroll
        for (int ct = 0; ct < 4; ++ct) {
            float A = 1.f, B = 0.f;
            if (FWD) {
                #pragma unroll
                for (int r = 0; r < 4; ++r) { A = av[rt][ct][r] * A; B = fmaf(av[rt][ct][r], B, bv[rt][ct][r]); }
            } else {
                #pragma unroll
                for (int r = 3; r >= 0; --r) { A = av[rt][ct][r] * A; B = fmaf(av[rt][ct][r], B, bv[rt][ct][r]); }
            }
            int seg = w * 8 + rt * 4 + quad;
            int col = ct * 16 + lr;
            sh.ep.segA[seg][col] = A;
            sh.ep.segB[seg][col] = B;
        }
    if (ABOUT) {
        #pragma unroll
        for (int rt = 0; rt < 2; ++rt)
            #pragma unroll
            for (int ct = 0; ct < 4; ++ct) {
                size_t base = (size_t)(t0 + w * 32 + rt * 16 + quad * 4) * D
                              + n0 + ct * 16 + lr;
                #pragma unroll
                for (int r = 0; r < 4; ++r) {
                    u32 pv = (u32)f2b(av[rt][ct][r]) | ((u32)f2b(bv[rt][ct][r]) << 16);
                    abg[base + (size_t)r * D] = pv;
                }
            }
    }
    __syncthreads();

    if (tid < BN) {
        float A = 1.f, B = 0.f;
        if (FWD) {
            #pragma unroll
            for (int sg = 0; sg < NSEG; ++sg) {
                float a = sh.ep.segA[sg][tid];
                A = a * A; B = fmaf(a, B, sh.ep.segB[sg][tid]);
            }
        } else {
            #pragma unroll
            for (int sg = NSEG - 1; sg >= 0; --sg) {
                float a = sh.ep.segA[sg][tid];
                A = a * A; B = fmaf(a, B, sh.ep.segB[sg][tid]);
            }
        }
        aggA[(size_t)c * D + n0 + tid] = A;
        aggB[(size_t)c * D + n0 + tid] = B;
    }
}

// ===========================================================================
// FUSED fwd+bwd GEMM: one A-staging feeds 6 B-streams / 48 MFMA per slice.
// Emits fwd and bwd chunk aggregates + packed ab_f / ab_b.
// ===========================================================================
__global__ __launch_bounds__(256) void qrn_g5fb(
    const u16* __restrict__ xbg, const u16* __restrict__ qg,
    const u16* __restrict__ xqg,
    const u16* __restrict__ wtF, const u16* __restrict__ wtB,
    const float* __restrict__ bzf, const float* __restrict__ bhf,
    const float* __restrict__ bzb, const float* __restrict__ bhb,
    float* __restrict__ aggAf, float* __restrict__ aggBf,
    float* __restrict__ aggAb, float* __restrict__ aggBb,
    u32* __restrict__ abf, u32* __restrict__ abb)
{
    __shared__ SharedF sh;
    const int tid  = threadIdx.x;
    const int gidx = ((int)blockIdx.x & 7) * 256 + ((int)blockIdx.x >> 3);
    const int c    = gidx >> 2;
    const int n0   = (gidx & 3) * BN;
    const int t0   = c * BT;
    const int lane = tid & 63, w = tid >> 6;
    const int lr   = lane & 15, quad = lane >> 4;

    int offA[2], offB[4];
    #pragma unroll
    for (int rt = 0; rt < 2; ++rt) {
        int row = w * 32 + rt * 16 + lr;
        offA[rt] = row * 32 + (quad ^ ((row >> 1) & 3)) * 8;
    }
    #pragma unroll
    for (int ct = 0; ct < 4; ++ct) {
        int n = ct * 16 + lr;
        offB[ct] = n * 32 + (quad ^ ((n >> 1) & 3)) * 8;
    }

    floatx4 acczf[2][4], acchf[2][4], acczb[2][4], acchb[2][4];
    #pragma unroll
    for (int rt = 0; rt < 2; ++rt)
        #pragma unroll
        for (int ct = 0; ct < 4; ++ct) {
            acczf[rt][ct] = (floatx4){0.f,0.f,0.f,0.f};
            acchf[rt][ct] = (floatx4){0.f,0.f,0.f,0.f};
            acczb[rt][ct] = (floatx4){0.f,0.f,0.f,0.f};
            acchb[rt][ct] = (floatx4){0.f,0.f,0.f,0.f};
        }

    const u16* wzf = wtF;
    const u16* wxf = wtF + 65536;
    const u16* wqf = wtF + 131072;
    const u16* wzb = wtB;
    const u16* wxb = wtB + 65536;
    const u16* wqb = wtB + 131072;
    const int wbase = (tid & ~63) * 8;

    for (int k0 = 0; k0 < D; k0 += 32) {
        #pragma unroll
        for (int i = 0; i < 2; ++i) {
            int u = i * 256 + tid;
            int row = u >> 2, sl = u & 3;
            int gg = sl ^ ((row >> 1) & 3);
            size_t go = (size_t)(t0 + row) * D + k0 + gg * 8;
            int lb = (i * 256 + (tid & ~63)) * 8;
            async16(xbg + go, sh.st.ax  + lb);
            async16(qg  + go, sh.st.aq  + lb);
            async16(xqg + go, sh.st.axq + lb);
        }
        {
            int n = tid >> 2, sl = tid & 3;
            int gg = sl ^ ((n >> 1) & 3);
            size_t go = (size_t)(n0 + n) * D + k0 + gg * 8;
            async16(wzf + go, sh.st.bzf_ + wbase);
            async16(wxf + go, sh.st.bxf_ + wbase);
            async16(wqf + go, sh.st.bqf_ + wbase);
            async16(wzb + go, sh.st.bzb_ + wbase);
            async16(wxb + go, sh.st.bxb_ + wbase);
            async16(wqb + go, sh.st.bqb_ + wbase);
        }
        __syncthreads();

        short8 fx[2], fq[2], fxq[2];
        #pragma unroll
        for (int rt = 0; rt < 2; ++rt) {
            fx [rt] = *(const short8*)(sh.st.ax  + offA[rt]);
            fq [rt] = *(const short8*)(sh.st.aq  + offA[rt]);
            fxq[rt] = *(const short8*)(sh.st.axq + offA[rt]);
        }
        #pragma unroll
        for (int ct = 0; ct < 4; ++ct) {
            short8 vzf = *(const short8*)(sh.st.bzf_ + offB[ct]);
            short8 vxf = *(const short8*)(sh.st.bxf_ + offB[ct]);
            short8 vqf = *(const short8*)(sh.st.bqf_ + offB[ct]);
            short8 vzb = *(const short8*)(sh.st.bzb_ + offB[ct]);
            short8 vxb = *(const short8*)(sh.st.bxb_ + offB[ct]);
            short8 vqb = *(const short8*)(sh.st.bqb_ + offB[ct]);
            #pragma unroll
            for (int rt = 0; rt < 2; ++rt) {
                acczf[rt][ct] = __builtin_amdgcn_mfma_f32_16x16x32_bf16(fxq[rt], vzf, acczf[rt][ct], 0, 0, 0);
                acchf[rt][ct] = __builtin_amdgcn_mfma_f32_16x16x32_bf16(fx [rt], vxf, acchf[rt][ct], 0, 0, 0);
                acchf[rt][ct] = __builtin_amdgcn_mfma_f32_16x16x32_bf16(fq [rt], vqf, acchf[rt][ct], 0, 0, 0);
                acczb[rt][ct] = __builtin_amdgcn_mfma_f32_16x16x32_bf16(fxq[rt], vzb, acczb[rt][ct], 0, 0, 0);
                acchb[rt][ct] = __builtin_amdgcn_mfma_f32_16x16x32_bf16(fx [rt], vxb, acchb[rt][ct], 0, 0, 0);
                acchb[rt][ct] = __builtin_amdgcn_mfma_f32_16x16x32_bf16(fq [rt], vqb, acchb[rt][ct], 0, 0, 0);
            }
        }
        __syncthreads();
    }

    // ---- epilogue FWD: per-microtile to completion (limits live registers)
    #pragma unroll
    for (int rt = 0; rt < 2; ++rt)
        #pragma unroll
        for (int ct = 0; ct < 4; ++ct) {
            int n = n0 + ct * 16 + lr;
            float bzn = bzf[n], bhn = bhf[n];
            float a4[4], b4[4];
            #pragma unroll
            for (int r = 0; r < 4; ++r) {
                float z  = sigm(acczf[rt][ct][r] + bzn);
                float ht = tanhfast(acchf[rt][ct][r] + bhn);
                a4[r] = 1.0f - z;
                b4[r] = z * ht;
            }
            float A = 1.f, B = 0.f;
            #pragma unroll
            for (int r = 0; r < 4; ++r) { A = a4[r] * A; B = fmaf(a4[r], B, b4[r]); }
            int seg = w * 8 + rt * 4 + quad;
            int col = ct * 16 + lr;
            sh.ep.segAf[seg][col] = A;
            sh.ep.segBf[seg][col] = B;
            size_t base = (size_t)(t0 + w * 32 + rt * 16 + quad * 4) * D + n;
            #pragma unroll
            for (int r = 0; r < 4; ++r)
                abf[base + (size_t)r * D] = (u32)f2b(a4[r]) | ((u32)f2b(b4[r]) << 16);
        }
    // ---- epilogue BWD
    #pragma unroll
    for (int rt = 0; rt < 2; ++rt)
        #pragma unroll
        for (int ct = 0; ct < 4; ++ct) {
            int n = n0 + ct * 16 + lr;
            float bzn = bzb[n], bhn = bhb[n];
            float a4[4], b4[4];
            #pragma unroll
            for (int r = 0; r < 4; ++r) {
                float z  = sigm(acczb[rt][ct][r] + bzn);
                float ht = tanhfast(acchb[rt][ct][r] + bhn);
                a4[r] = 1.0f - z;
                b4[r] = z * ht;
            }
            float A = 1.f, B = 0.f;
            #pragma unroll
            for (int r = 3; r >= 0; --r) { A = a4[r] * A; B = fmaf(a4[r], B, b4[r]); }
            int seg = w * 8 + rt * 4 + quad;
            int col = ct * 16 + lr;
            sh.ep.segAb[seg][col] = A;
            sh.ep.segBb[seg][col] = B;
            size_t base = (size_t)(t0 + w * 32 + rt * 16 + quad * 4) * D + n;
            #pragma unroll
            for (int r = 0; r < 4; ++r)
                abb[base + (size_t)r * D] = (u32)f2b(a4[r]) | ((u32)f2b(b4[r]) << 16);
        }
    __syncthreads();

    if (tid < BN) {
        float A = 1.f, B = 0.f;
        #pragma unroll
        for (int sg = 0; sg < NSEG; ++sg) {
            float a = sh.ep.segAf[sg][tid];
            A = a * A; B = fmaf(a, B, sh.ep.segBf[sg][tid]);
        }
        aggAf[(size_t)c * D + n0 + tid] = A;
        aggBf[(size_t)c * D + n0 + tid] = B;
        A = 1.f; B = 0.f;
        #pragma unroll
        for (int sg = NSEG - 1; sg >= 0; --sg) {
            float a = sh.ep.segAb[sg][tid];
            A = a * A; B = fmaf(a, B, sh.ep.segBb[sg][tid]);
        }
        aggAb[(size_t)c * D + n0 + tid] = A;
        aggBb[(size_t)c * D + n0 + tid] = B;
    }
}

// ===========================================================================
// replay kernels: read packed a,b; seg-scan per channel; write h.
// ===========================================================================
__global__ __launch_bounds__(256) void replay_f(
    const u32* __restrict__ abg, const float* __restrict__ hini,
    u16* __restrict__ qout)
{
    __shared__ u32   sab[BT * BN];       // 32 KB
    __shared__ float sA[4][BN], sB[4][BN], hs[4][BN];
    const int tid = threadIdx.x;
    const int c   = (int)(blockIdx.x >> 2);
    const int n0  = ((int)blockIdx.x & 3) * BN;
    const int t0  = c * BT;

    #pragma unroll
    for (int i = 0; i < 8; ++i) {
        int idx = i * 256 + tid;
        int row = idx >> 4, g = idx & 15;
        *(uint4*)(sab + row * BN + g * 4) =
            *(const uint4*)(abg + (size_t)(t0 + row) * D + n0 + g * 4);
    }
    __syncthreads();

    const int sg = tid >> 6, n = tid & 63;
    float A = 1.f, B = 0.f;
    #pragma unroll
    for (int i = 0; i < 32; ++i) {
        u32 v = sab[(sg * 32 + i) * BN + n];
        float a = b2f((u16)(v & 0xffff)), b = b2f((u16)(v >> 16));
        A = a * A; B = fmaf(a, B, b);
    }
    sA[sg][n] = A; sB[sg][n] = B;
    __syncthreads();
    if (tid < BN) {
        float h = hini[(size_t)c * D + n0 + tid];
        #pragma unroll
        for (int s = 0; s < 4; ++s) {
            hs[s][tid] = h;
            h = fmaf(sA[s][tid], h, sB[s][tid]);
        }
    }
    __syncthreads();
    float h = hs[sg][n];
    #pragma unroll
    for (int i = 0; i < 32; ++i) {
        int t = sg * 32 + i;
        u32 v = sab[t * BN + n];
        float a = b2f((u16)(v & 0xffff)), b = b2f((u16)(v >> 16));
        h = fmaf(a, h, b);
        qout[(size_t)(t0 + t) * D + n0 + n] = f2b(h);
    }
}

__global__ __launch_bounds__(256) void replay_b(
    const u32* __restrict__ abg, const float* __restrict__ hini,
    const u16* __restrict__ xb, u16* __restrict__ qout, u16* __restrict__ xq)
{
    __shared__ u32   sab[BT * BN];
    __shared__ float sA[4][BN], sB[4][BN], hs[4][BN];
    const int tid = threadIdx.x;
    const int c   = (int)(blockIdx.x >> 2);
    const int n0  = ((int)blockIdx.x & 3) * BN;
    const int t0  = c * BT;

    #pragma unroll
    for (int i = 0; i < 8; ++i) {
        int idx = i * 256 + tid;
        int row = idx >> 4, g = idx & 15;
        *(uint4*)(sab + row * BN + g * 4) =
            *(const uint4*)(abg + (size_t)(t0 + row) * D + n0 + g * 4);
    }
    __syncthreads();

    const int sg = tid >> 6, n = tid & 63;
    float A = 1.f, B = 0.f;
    #pragma unroll
    for (int i = 31; i >= 0; --i) {
        u32 v = sab[(sg * 32 + i) * BN + n];
        float a = b2f((u16)(v & 0xffff)), b = b2f((u16)(v >> 16));
        A = a * A; B = fmaf(a, B, b);
    }
    sA[sg][n] = A; sB[sg][n] = B;
    __syncthreads();
    if (tid < BN) {
        float h = hini[(size_t)c * D + n0 + tid];
        for (int s = 3; s >= 0; --s) {
            hs[s][tid] = h;
            h = fmaf(sA[s][tid], h, sB[s][tid]);
        }
    }
    __syncthreads();
    float h = hs[sg][n];
    #pragma unroll
    for (int i = 31; i >= 0; --i) {
        int t = sg * 32 + i;
        u32 v = sab[t * BN + n];
        float a = b2f((u16)(v & 0xffff)), b = b2f((u16)(v >> 16));
        h = fmaf(a, h, b);
        size_t o = (size_t)(t0 + t) * D + n0 + n;
        float qn = b2f(qout[o]) + h;       // hF + hB
        u16 qb = f2b(qn);
        qout[o] = qb;
        xq[o]   = f2b(b2f(xb[o]) * b2f(qb));
    }
}

// ---------------------------------------------------------------------------
// inter-chunk scans
// ---------------------------------------------------------------------------
__device__ __forceinline__ void scan_body(
    const float* aggA, const float* aggB, float* hinit, float* out_final,
    int fwd, int nch, int n, int tid)
{
    __shared__ float sA[256], sB[256];
    const int per = nch >> 8;
    float lA[4], lB[4];
    float A = 1.f, B = 0.f;
    for (int j = 0; j < per; ++j) {
        int pidx = tid * per + j;
        int c = fwd ? pidx : (nch - 1 - pidx);
        float a = aggA[(size_t)c * D + n];
        float b = aggB[(size_t)c * D + n];
        lA[j] = a; lB[j] = b;
        A = a * A;
        B = fmaf(a, B, b);
    }
    sA[tid] = A; sB[tid] = B;
    __syncthreads();
    for (int off = 1; off < 256; off <<= 1) {
        float pA = 1.f, pB = 0.f;
        if (tid >= off) { pA = sA[tid - off]; pB = sB[tid - off]; }
        __syncthreads();
        if (tid >= off) {
            float cA = sA[tid], cB = sB[tid];
            sA[tid] = pA * cA;
            sB[tid] = fmaf(cA, pB, cB);
        }
        __syncthreads();
    }
    float eB = (tid > 0) ? sB[tid - 1] : 0.f;
    for (int j = 0; j < per; ++j) {
        int pidx = tid * per + j;
        int c = fwd ? pidx : (nch - 1 - pidx);
        hinit[(size_t)c * D + n] = eB;
        eB = fmaf(lA[j], eB, lB[j]);
    }
    if (out_final != nullptr && tid == 0) out_final[n] = sB[255];
}

__global__ __launch_bounds__(256) void scan_p2_kernel(
    const float* __restrict__ aggA, const float* __restrict__ aggB,
    float* __restrict__ hinit, float* __restrict__ out_final, int fwd, int nch)
{
    scan_body(aggA, aggB, hinit, out_final, fwd, nch, blockIdx.x, threadIdx.x);
}

__global__ __launch_bounds__(256) void scan_dual_kernel(
    const float* __restrict__ aggAf, const float* __restrict__ aggBf, float* __restrict__ hf,
    const float* __restrict__ aggAb, const float* __restrict__ aggBb, float* __restrict__ hb,
    int nch)
{
    int b = blockIdx.x;
    int fwd = (b < D) ? 1 : 0;
    int n = fwd ? b : (b - D);
    scan_body(fwd ? aggAf : aggAb, fwd ? aggBf : aggBb,
              fwd ? hf : hb, nullptr, fwd, nch, n, threadIdx.x);
}

// ---------------------------------------------------------------------------
extern "C" void kernel_launch(void* const* d_in, const int* in_sizes, int n_in,
                              void* d_out, int out_size, void* d_ws, size_t ws_size,
                              hipStream_t stream) {
    const float* story    = (const float*)d_in[0];
    const float* question = (const float*)d_in[1];
    const float* Wz_f = (const float*)d_in[2];
    const float* bz_f = (const float*)d_in[3];
    const float* Wh_f = (const float*)d_in[4];
    const float* bh_f = (const float*)d_in[5];
    const float* Wz_b = (const float*)d_in[6];
    const float* bz_b = (const float*)d_in[7];
    const float* Wh_b = (const float*)d_in[8];
    const float* bh_b = (const float*)d_in[9];

    const int T    = in_sizes[0] / D;            // 65536
    const int NCH  = T / BT;                     // 512
    const size_t TD = (size_t)T * D;
    const size_t WTE = 5 * 3 * 65536;

    // plan F (fused): xb,q,xq + wt + abf,abb + 4 agg arrays  (~239 MB)
    const size_t needF = 3 * TD * 2 + WTE * 2 + 2 * TD * 4
                       + (size_t)4 * NCH * D * 4 + 4096;
    const bool planF = ws_size >= needF;

    dim3 blk(256);
    dim3 gGrid((unsigned)(NCH * 4));             // 2048
    dim3 pGrid((unsigned)(TD / 8 / 256));

    if (planF) {
        u16* xb = (u16*)d_ws;
        u16* q  = xb + TD;
        u16* xq = q  + TD;
        u16* wt = xq + TD;
        u32* abf = (u32*)(wt + WTE);
        u32* abb = abf + TD;
        float* aggAf = (float*)(abb + TD);
        float* aggBf = aggAf + (size_t)NCH * D;
        float* aggAb = aggBf + (size_t)NCH * D;
        float* aggBb = aggAb + (size_t)NCH * D;
        float* hinif = aggBf;                    // alias (safe)
        float* hinib = aggBb;                    // alias (safe)

        wtrans_kernel<<<dim3(5 * 3 * 65536 / 256), blk, 0, stream>>>(
            Wz_f, Wh_f, Wz_b, Wh_b, wt);
        prep0_kernel<<<pGrid, blk, 0, stream>>>(story, question, xb, q, xq);

        for (int l = 0; l < 3; ++l) {
            const u16*   wtf = wt + (size_t)l * 3 * 65536;
            const float* bzf = bz_f + (size_t)l * D;
            const float* bhf = bh_f + (size_t)l * D;

            if (l == 2) {
                qrn_g5<1,0><<<gGrid, blk, 0, stream>>>(
                    xb, q, xq, wtf, bzf, bhf, aggAf, aggBf, nullptr);
                scan_p2_kernel<<<dim3(D), blk, 0, stream>>>(
                    aggAf, aggBf, hinif, (float*)d_out, 1, NCH);
                break;
            }
            const u16*   wtb = wt + (size_t)(3 + l) * 3 * 65536;
            const float* bzb = bz_b + (size_t)l * D;
            const float* bhb = bh_b + (size_t)l * D;

            qrn_g5fb<<<gGrid, blk, 0, stream>>>(
                xb, q, xq, wtf, wtb, bzf, bhf, bzb, bhb,
                aggAf, aggBf, aggAb, aggBb, abf, abb);
            scan_dual_kernel<<<dim3(2 * D), blk, 0, stream>>>(
                aggAf, aggBf, hinif, aggAb, aggBb, hinib, NCH);
            replay_f<<<gGrid, blk, 0, stream>>>(abf, hinif, q);   // in-place q
            replay_b<<<gGrid, blk, 0, stream>>>(abb, hinib, xb, q, xq);
        }
    } else {
        // ---------------- plan P (R6, proven at 683 us) ----------------
        u16* xb = (u16*)d_ws;
        u16* qA = xb + TD;
        u16* qB = qA + TD;
        u16* xq = qB + TD;
        u16* wt = xq + TD;
        u32*   ab   = (u32*)(wt + WTE);
        float* aggA = (float*)(ab + TD);
        float* aggB = aggA + (size_t)NCH * D;
        float* hini = aggB;

        wtrans_kernel<<<dim3(5 * 3 * 65536 / 256), blk, 0, stream>>>(
            Wz_f, Wh_f, Wz_b, Wh_b, wt);
        prep0_kernel<<<pGrid, blk, 0, stream>>>(story, question, xb, qA, xq);

        const u16* qcur  = qA;
        u16*       qnext = qB;

        for (int l = 0; l < 3; ++l) {
            const u16*   wtf = wt + (size_t)l * 3 * 65536;
            const float* bzf = bz_f + (size_t)l * D;
            const float* bhf = bh_f + (size_t)l * D;

            if (l == 2) {
                qrn_g5<1,0><<<gGrid, blk, 0, stream>>>(
                    xb, qcur, xq, wtf, bzf, bhf, aggA, aggB, nullptr);
                scan_p2_kernel<<<dim3(D), blk, 0, stream>>>(
                    aggA, aggB, hini, (float*)d_out, 1, NCH);
                break;
            }
            const u16*   wtb = wt + (size_t)(3 + l) * 3 * 65536;
            const float* bzb = bz_b + (size_t)l * D;
            const float* bhb = bh_b + (size_t)l * D;

            qrn_g5<1,1><<<gGrid, blk, 0, stream>>>(
                xb, qcur, xq, wtf, bzf, bhf, aggA, aggB, ab);
            scan_p2_kernel<<<dim3(D), blk, 0, stream>>>(aggA, aggB, hini, nullptr, 1, NCH);
            replay_f<<<gGrid, blk, 0, stream>>>(ab, hini, qnext);

            qrn_g5<0,1><<<gGrid, blk, 0, stream>>>(
                xb, qcur, xq, wtb, bzb, bhb, aggA, aggB, ab);
            scan_p2_kernel<<<dim3(D), blk, 0, stream>>>(aggA, aggB, hini, nullptr, 0, NCH);
            replay_b<<<gGrid, blk, 0, stream>>>(ab, hini, xb, qnext, xq);

            const u16* ts = qcur; qcur = qnext; qnext = (u16*)ts;
        }
    }
}

// Round 8
// 647.545 us; speedup vs baseline: 1.1850x; 1.1850x over previous
//
#include <hip/hip_runtime.h>
#include <hip/hip_bf16.h>
#include <math.h>

#define D    256
#define BT   128     // chunk length == M tile
#define BN   64      // N tile per block (4 N-slices)
#define NSEG 32      // BT/4 segments per chunk (GEMM epilogue)

typedef unsigned short u16;
typedef unsigned int   u32;
typedef __attribute__((ext_vector_type(8))) short short8;   // 8 bf16 = 4 VGPRs
typedef __attribute__((ext_vector_type(4))) float floatx4;  // MFMA C/D frag

__device__ __forceinline__ float b2f(u16 v) {
    union { unsigned u; float f; } x; x.u = ((unsigned)v) << 16; return x.f;
}
__device__ __forceinline__ u16 f2b(float f) {
    union { unsigned u; float f; } x; x.f = f;
    unsigned lsb = (x.u >> 16) & 1;
    x.u += 0x7fffu + lsb;                 // RNE
    return (u16)(x.u >> 16);
}
__device__ __forceinline__ float sigm(float x) {
    return __builtin_amdgcn_rcpf(1.0f + __expf(-x));
}
__device__ __forceinline__ float tanhfast(float x) {
    return 1.0f - 2.0f * __builtin_amdgcn_rcpf(__expf(2.0f * x) + 1.0f);
}
__device__ __forceinline__ void async16(const u16* g, u16* l) {
    __builtin_amdgcn_global_load_lds(
        (const __attribute__((address_space(1))) unsigned int*)g,
        (__attribute__((address_space(3))) unsigned int*)l, 16, 0, 0);
}

// ---------------------------------------------------------------------------
// weight transpose + bf16 cast: wt[combo][m][n][k] = bf16(W[k][n])
// ---------------------------------------------------------------------------
__global__ __launch_bounds__(256) void wtrans_kernel(
    const float* __restrict__ Wz_f, const float* __restrict__ Wh_f,
    const float* __restrict__ Wz_b, const float* __restrict__ Wh_b,
    u16* __restrict__ wt)
{
    int id = blockIdx.x * 256 + threadIdx.x;       // < 5*3*65536
    int combo = id / (3 * 65536);
    int rem   = id % (3 * 65536);
    int m = rem >> 16;
    int e = rem & 65535;
    int k = e >> 8, n = e & 255;
    int l   = combo < 3 ? combo : combo - 3;
    int dir = combo < 3 ? 0 : 1;
    float v;
    if (m == 0) {
        const float* Wz = dir ? Wz_b : Wz_f;
        v = Wz[((size_t)l * D + k) * D + n];
    } else {
        const float* Wh = dir ? Wh_b : Wh_f;
        int kk = (m == 2) ? (k + D) : k;
        v = Wh[((size_t)l * 2 * D + kk) * D + n];
    }
    wt[(size_t)combo * 3 * 65536 + (size_t)m * 65536 + (size_t)n * D + k] = f2b(v);
}

// ---------------------------------------------------------------------------
// prep: xb = bf16(x), q broadcast, xq = bf16(x*qbf)
// ---------------------------------------------------------------------------
__global__ __launch_bounds__(256) void prep0_kernel(
    const float* __restrict__ story, const float* __restrict__ question,
    u16* __restrict__ xb, u16* __restrict__ q, u16* __restrict__ xq)
{
    long id = (long)blockIdx.x * 256 + threadIdx.x;
    long row = id >> 5;
    int  d0  = (int)(id & 31) * 8;
    const float* xp = story + row * D + d0;
    float4 xa = *(const float4*)xp;
    float4 xc = *(const float4*)(xp + 4);
    float xv[8] = {xa.x, xa.y, xa.z, xa.w, xc.x, xc.y, xc.z, xc.w};
    short8 xs, qs, xqs;
    #pragma unroll
    for (int i = 0; i < 8; ++i) {
        u16 qb = f2b(question[d0 + i]);
        xs[i]  = (short)f2b(xv[i]);
        qs[i]  = (short)qb;
        xqs[i] = (short)f2b(xv[i] * b2f(qb));
    }
    long o = id * 8;
    *(short8*)(xb + o) = xs;
    *(short8*)(q  + o) = qs;
    *(short8*)(xq + o) = xqs;
}

// ---------------------------------------------------------------------------
// LDS stage layout
// ---------------------------------------------------------------------------
struct StageS {
    u16 ax [BT * 32]; u16 aq [BT * 32]; u16 axq[BT * 32];   // 8KB each
    u16 bz_[BN * 32]; u16 bx_[BN * 32]; u16 bq_[BN * 32];   // 4KB each
};
struct EpiP { float segA[NSEG][BN]; float segB[NSEG][BN]; };
union SharedP { StageS st; EpiP ep; };

// ---------------------------------------------------------------------------
// shared GEMM body: stages A/B, runs MFMA, computes gates, seg-aggregates,
// optional packed ab writeout, chunk aggregate. FWD is runtime wave-uniform.
// ---------------------------------------------------------------------------
__device__ __forceinline__ void gemm_body(
    SharedP& sh, int tid, int c, int n0,
    const u16* xbg, const u16* qg, const u16* xqg, const u16* wt,
    const float* bz, const float* bh,
    float* aggA, float* aggB, u32* abg, int FWD)
{
    const int t0   = c * BT;
    const int lane = tid & 63, w = tid >> 6;
    const int lr   = lane & 15, quad = lane >> 4;

    int offA[2], offB[4];
    #pragma unroll
    for (int rt = 0; rt < 2; ++rt) {
        int row = w * 32 + rt * 16 + lr;
        offA[rt] = row * 32 + (quad ^ ((row >> 1) & 3)) * 8;
    }
    #pragma unroll
    for (int ct = 0; ct < 4; ++ct) {
        int n = ct * 16 + lr;
        offB[ct] = n * 32 + (quad ^ ((n >> 1) & 3)) * 8;
    }

    floatx4 accz[2][4], acch[2][4];
    #pragma unroll
    for (int rt = 0; rt < 2; ++rt)
        #pragma unroll
        for (int ct = 0; ct < 4; ++ct) {
            accz[rt][ct] = (floatx4){0.f,0.f,0.f,0.f};
            acch[rt][ct] = (floatx4){0.f,0.f,0.f,0.f};
        }

    const u16* wz = wt;
    const u16* wx = wt + 65536;
    const u16* wq = wt + 131072;
    const int wbase = (tid & ~63) * 8;

    for (int k0 = 0; k0 < D; k0 += 32) {
        #pragma unroll
        for (int i = 0; i < 2; ++i) {
            int u = i * 256 + tid;
            int row = u >> 2, sl = u & 3;
            int gg = sl ^ ((row >> 1) & 3);
            size_t go = (size_t)(t0 + row) * D + k0 + gg * 8;
            int lb = (i * 256 + (tid & ~63)) * 8;
            async16(xbg + go, sh.st.ax  + lb);
            async16(qg  + go, sh.st.aq  + lb);
            async16(xqg + go, sh.st.axq + lb);
        }
        {
            int n = tid >> 2, sl = tid & 3;
            int gg = sl ^ ((n >> 1) & 3);
            size_t go = (size_t)(n0 + n) * D + k0 + gg * 8;
            async16(wz + go, sh.st.bz_ + wbase);
            async16(wx + go, sh.st.bx_ + wbase);
            async16(wq + go, sh.st.bq_ + wbase);
        }
        __syncthreads();

        short8 fx[2], fq[2], fxq[2];
        #pragma unroll
        for (int rt = 0; rt < 2; ++rt) {
            fx [rt] = *(const short8*)(sh.st.ax  + offA[rt]);
            fq [rt] = *(const short8*)(sh.st.aq  + offA[rt]);
            fxq[rt] = *(const short8*)(sh.st.axq + offA[rt]);
        }
        #pragma unroll
        for (int ct = 0; ct < 4; ++ct) {
            short8 vz = *(const short8*)(sh.st.bz_ + offB[ct]);
            short8 vx = *(const short8*)(sh.st.bx_ + offB[ct]);
            short8 vq = *(const short8*)(sh.st.bq_ + offB[ct]);
            #pragma unroll
            for (int rt = 0; rt < 2; ++rt) {
                accz[rt][ct] = __builtin_amdgcn_mfma_f32_16x16x32_bf16(fxq[rt], vz, accz[rt][ct], 0, 0, 0);
                acch[rt][ct] = __builtin_amdgcn_mfma_f32_16x16x32_bf16(fx [rt], vx, acch[rt][ct], 0, 0, 0);
                acch[rt][ct] = __builtin_amdgcn_mfma_f32_16x16x32_bf16(fq [rt], vq, acch[rt][ct], 0, 0, 0);
            }
        }
        __syncthreads();
    }

    // gate epilogue (C/D: col = lr, rows = quad*4 + r)
    float av[2][4][4], bv[2][4][4];
    #pragma unroll
    for (int ct = 0; ct < 4; ++ct) {
        int n = n0 + ct * 16 + lr;
        float bzn = bz[n], bhn = bh[n];
        #pragma unroll
        for (int rt = 0; rt < 2; ++rt)
            #pragma unroll
            for (int r = 0; r < 4; ++r) {
                float z  = sigm(accz[rt][ct][r] + bzn);
                float ht = tanhfast(acch[rt][ct][r] + bhn);
                av[rt][ct][r] = 1.0f - z;
                bv[rt][ct][r] = z * ht;
            }
    }
    #pragma unroll
    for (int rt = 0; rt < 2; ++rt)
        #pragma unroll
        for (int ct = 0; ct < 4; ++ct) {
            float A = 1.f, B = 0.f;
            if (FWD) {
                #pragma unroll
                for (int r = 0; r < 4; ++r) { A = av[rt][ct][r] * A; B = fmaf(av[rt][ct][r], B, bv[rt][ct][r]); }
            } else {
                #pragma unroll
                for (int r = 3; r >= 0; --r) { A = av[rt][ct][r] * A; B = fmaf(av[rt][ct][r], B, bv[rt][ct][r]); }
            }
            int seg = w * 8 + rt * 4 + quad;
            int col = ct * 16 + lr;
            sh.ep.segA[seg][col] = A;
            sh.ep.segB[seg][col] = B;
        }
    if (abg) {
        #pragma unroll
        for (int rt = 0; rt < 2; ++rt)
            #pragma unroll
            for (int ct = 0; ct < 4; ++ct) {
                size_t base = (size_t)(t0 + w * 32 + rt * 16 + quad * 4) * D
                              + n0 + ct * 16 + lr;
                #pragma unroll
                for (int r = 0; r < 4; ++r) {
                    u32 pv = (u32)f2b(av[rt][ct][r]) | ((u32)f2b(bv[rt][ct][r]) << 16);
                    abg[base + (size_t)r * D] = pv;
                }
            }
    }
    __syncthreads();

    if (tid < BN) {
        float A = 1.f, B = 0.f;
        if (FWD) {
            #pragma unroll
            for (int sg = 0; sg < NSEG; ++sg) {
                float a = sh.ep.segA[sg][tid];
                A = a * A; B = fmaf(a, B, sh.ep.segB[sg][tid]);
            }
        } else {
            #pragma unroll
            for (int sg = NSEG - 1; sg >= 0; --sg) {
                float a = sh.ep.segA[sg][tid];
                A = a * A; B = fmaf(a, B, sh.ep.segB[sg][tid]);
            }
        }
        aggA[(size_t)c * D + n0 + tid] = A;
        aggB[(size_t)c * D + n0 + tid] = B;
    }
}

// single-direction GEMM (layer 2 fwd; plan P)
template<int FWD, int ABOUT>
__global__ __launch_bounds__(256) void qrn_g5(
    const u16* __restrict__ xbg, const u16* __restrict__ qg,
    const u16* __restrict__ xqg, const u16* __restrict__ wt,
    const float* __restrict__ bz, const float* __restrict__ bh,
    float* __restrict__ aggA, float* __restrict__ aggB,
    u32* __restrict__ abg)
{
    __shared__ SharedP sh;
    const int tid  = threadIdx.x;
    const int gidx = ((int)blockIdx.x & 7) * 256 + ((int)blockIdx.x >> 3);
    gemm_body(sh, tid, gidx >> 2, (gidx & 3) * BN,
              xbg, qg, xqg, wt, bz, bh, aggA, aggB, ABOUT ? abg : nullptr, FWD);
}

// combined fwd+bwd GEMM: blocks [0,2048) = fwd, [2048,4096) = bwd.
// Per-block footprint identical to qrn_g5 (100 VGPR-class, 36 KB LDS).
__global__ __launch_bounds__(256) void qrn_gboth(
    const u16* __restrict__ xbg, const u16* __restrict__ qg,
    const u16* __restrict__ xqg,
    const u16* __restrict__ wtF, const u16* __restrict__ wtB,
    const float* __restrict__ bzf, const float* __restrict__ bhf,
    const float* __restrict__ bzb, const float* __restrict__ bhb,
    float* __restrict__ aggAf, float* __restrict__ aggBf,
    float* __restrict__ aggAb, float* __restrict__ aggBb,
    u32* __restrict__ abf, u32* __restrict__ abb)
{
    __shared__ SharedP sh;
    const int tid  = threadIdx.x;
    const int half = (int)blockIdx.x >> 11;       // 0=fwd, 1=bwd
    const int bid  = (int)blockIdx.x & 2047;
    const int gidx = (bid & 7) * 256 + (bid >> 3);
    gemm_body(sh, tid, gidx >> 2, (gidx & 3) * BN,
              xbg, qg, xqg,
              half ? wtB : wtF,
              half ? bzb : bzf, half ? bhb : bhf,
              half ? aggAb : aggAf, half ? aggBb : aggBf,
              half ? abb : abf, half ? 0 : 1);
}

// ===========================================================================
// fused replay: h_f pass (abf) -> bf16 LDS, then h_b pass (abb);
// writes q = h_f + h_b and xq = xb * q. Single-buffered q.
// ===========================================================================
__global__ __launch_bounds__(256) void replay_fb(
    const u32* __restrict__ abf, const u32* __restrict__ abb,
    const float* __restrict__ hinif, const float* __restrict__ hinib,
    const u16* __restrict__ xb, u16* __restrict__ qout, u16* __restrict__ xq)
{
    __shared__ u32   sab[BT * BN];       // 32 KB
    __shared__ u16   hf16[BT * BN];      // 16 KB
    __shared__ float sA[4][BN], sB[4][BN], hs[4][BN];
    const int tid = threadIdx.x;
    const int c   = (int)(blockIdx.x >> 2);
    const int n0  = ((int)blockIdx.x & 3) * BN;
    const int t0  = c * BT;
    const int sg = tid >> 6, n = tid & 63;

    // ---------------- pass 1: forward ----------------
    #pragma unroll
    for (int i = 0; i < 8; ++i) {
        int idx = i * 256 + tid;
        int row = idx >> 4, g = idx & 15;
        *(uint4*)(sab + row * BN + g * 4) =
            *(const uint4*)(abf + (size_t)(t0 + row) * D + n0 + g * 4);
    }
    __syncthreads();
    {
        float A = 1.f, B = 0.f;
        #pragma unroll
        for (int i = 0; i < 32; ++i) {
            u32 v = sab[(sg * 32 + i) * BN + n];
            float a = b2f((u16)(v & 0xffff)), b = b2f((u16)(v >> 16));
            A = a * A; B = fmaf(a, B, b);
        }
        sA[sg][n] = A; sB[sg][n] = B;
    }
    __syncthreads();
    if (tid < BN) {
        float h = hinif[(size_t)c * D + n0 + tid];
        #pragma unroll
        for (int s = 0; s < 4; ++s) {
            hs[s][tid] = h;
            h = fmaf(sA[s][tid], h, sB[s][tid]);
        }
    }
    __syncthreads();
    {
        float h = hs[sg][n];
        #pragma unroll
        for (int i = 0; i < 32; ++i) {
            int t = sg * 32 + i;
            u32 v = sab[t * BN + n];
            float a = b2f((u16)(v & 0xffff)), b = b2f((u16)(v >> 16));
            h = fmaf(a, h, b);
            hf16[t * BN + n] = f2b(h);
        }
    }
    __syncthreads();

    // ---------------- pass 2: backward + writeout ----------------
    #pragma unroll
    for (int i = 0; i < 8; ++i) {
        int idx = i * 256 + tid;
        int row = idx >> 4, g = idx & 15;
        *(uint4*)(sab + row * BN + g * 4) =
            *(const uint4*)(abb + (size_t)(t0 + row) * D + n0 + g * 4);
    }
    __syncthreads();
    {
        float A = 1.f, B = 0.f;
        #pragma unroll
        for (int i = 31; i >= 0; --i) {
            u32 v = sab[(sg * 32 + i) * BN + n];
            float a = b2f((u16)(v & 0xffff)), b = b2f((u16)(v >> 16));
            A = a * A; B = fmaf(a, B, b);
        }
        sA[sg][n] = A; sB[sg][n] = B;
    }
    __syncthreads();
    if (tid < BN) {
        float h = hinib[(size_t)c * D + n0 + tid];
        for (int s = 3; s >= 0; --s) {
            hs[s][tid] = h;
            h = fmaf(sA[s][tid], h, sB[s][tid]);
        }
    }
    __syncthreads();
    {
        float h = hs[sg][n];
        #pragma unroll
        for (int i = 31; i >= 0; --i) {
            int t = sg * 32 + i;
            u32 v = sab[t * BN + n];
            float a = b2f((u16)(v & 0xffff)), b = b2f((u16)(v >> 16));
            h = fmaf(a, h, b);
            size_t o = (size_t)(t0 + t) * D + n0 + n;
            float qn = b2f(hf16[t * BN + n]) + h;      // hF + hB
            u16 qb = f2b(qn);
            qout[o] = qb;
            xq[o]   = f2b(b2f(xb[o]) * b2f(qb));
        }
    }
}

// plan-P replay kernels (fallback)
__global__ __launch_bounds__(256) void replay_f(
    const u32* __restrict__ abg, const float* __restrict__ hini,
    u16* __restrict__ qout)
{
    __shared__ u32   sab[BT * BN];
    __shared__ float sA[4][BN], sB[4][BN], hs[4][BN];
    const int tid = threadIdx.x;
    const int c   = (int)(blockIdx.x >> 2);
    const int n0  = ((int)blockIdx.x & 3) * BN;
    const int t0  = c * BT;

    #pragma unroll
    for (int i = 0; i < 8; ++i) {
        int idx = i * 256 + tid;
        int row = idx >> 4, g = idx & 15;
        *(uint4*)(sab + row * BN + g * 4) =
            *(const uint4*)(abg + (size_t)(t0 + row) * D + n0 + g * 4);
    }
    __syncthreads();

    const int sg = tid >> 6, n = tid & 63;
    float A = 1.f, B = 0.f;
    #pragma unroll
    for (int i = 0; i < 32; ++i) {
        u32 v = sab[(sg * 32 + i) * BN + n];
        float a = b2f((u16)(v & 0xffff)), b = b2f((u16)(v >> 16));
        A = a * A; B = fmaf(a, B, b);
    }
    sA[sg][n] = A; sB[sg][n] = B;
    __syncthreads();
    if (tid < BN) {
        float h = hini[(size_t)c * D + n0 + tid];
        #pragma unroll
        for (int s = 0; s < 4; ++s) {
            hs[s][tid] = h;
            h = fmaf(sA[s][tid], h, sB[s][tid]);
        }
    }
    __syncthreads();
    float h = hs[sg][n];
    #pragma unroll
    for (int i = 0; i < 32; ++i) {
        int t = sg * 32 + i;
        u32 v = sab[t * BN + n];
        float a = b2f((u16)(v & 0xffff)), b = b2f((u16)(v >> 16));
        h = fmaf(a, h, b);
        qout[(size_t)(t0 + t) * D + n0 + n] = f2b(h);
    }
}

__global__ __launch_bounds__(256) void replay_b(
    const u32* __restrict__ abg, const float* __restrict__ hini,
    const u16* __restrict__ xb, u16* __restrict__ qout, u16* __restrict__ xq)
{
    __shared__ u32   sab[BT * BN];
    __shared__ float sA[4][BN], sB[4][BN], hs[4][BN];
    const int tid = threadIdx.x;
    const int c   = (int)(blockIdx.x >> 2);
    const int n0  = ((int)blockIdx.x & 3) * BN;
    const int t0  = c * BT;

    #pragma unroll
    for (int i = 0; i < 8; ++i) {
        int idx = i * 256 + tid;
        int row = idx >> 4, g = idx & 15;
        *(uint4*)(sab + row * BN + g * 4) =
            *(const uint4*)(abg + (size_t)(t0 + row) * D + n0 + g * 4);
    }
    __syncthreads();

    const int sg = tid >> 6, n = tid & 63;
    float A = 1.f, B = 0.f;
    #pragma unroll
    for (int i = 31; i >= 0; --i) {
        u32 v = sab[(sg * 32 + i) * BN + n];
        float a = b2f((u16)(v & 0xffff)), b = b2f((u16)(v >> 16));
        A = a * A; B = fmaf(a, B, b);
    }
    sA[sg][n] = A; sB[sg][n] = B;
    __syncthreads();
    if (tid < BN) {
        float h = hini[(size_t)c * D + n0 + tid];
        for (int s = 3; s >= 0; --s) {
            hs[s][tid] = h;
            h = fmaf(sA[s][tid], h, sB[s][tid]);
        }
    }
    __syncthreads();
    float h = hs[sg][n];
    #pragma unroll
    for (int i = 31; i >= 0; --i) {
        int t = sg * 32 + i;
        u32 v = sab[t * BN + n];
        float a = b2f((u16)(v & 0xffff)), b = b2f((u16)(v >> 16));
        h = fmaf(a, h, b);
        size_t o = (size_t)(t0 + t) * D + n0 + n;
        float qn = b2f(qout[o]) + h;
        u16 qb = f2b(qn);
        qout[o] = qb;
        xq[o]   = f2b(b2f(xb[o]) * b2f(qb));
    }
}

// ---------------------------------------------------------------------------
// inter-chunk scans
// ---------------------------------------------------------------------------
__device__ __forceinline__ void scan_body(
    const float* aggA, const float* aggB, float* hinit, float* out_final,
    int fwd, int nch, int n, int tid)
{
    __shared__ float sA[256], sB[256];
    const int per = nch >> 8;
    float lA[4], lB[4];
    float A = 1.f, B = 0.f;
    for (int j = 0; j < per; ++j) {
        int pidx = tid * per + j;
        int c = fwd ? pidx : (nch - 1 - pidx);
        float a = aggA[(size_t)c * D + n];
        float b = aggB[(size_t)c * D + n];
        lA[j] = a; lB[j] = b;
        A = a * A;
        B = fmaf(a, B, b);
    }
    sA[tid] = A; sB[tid] = B;
    __syncthreads();
    for (int off = 1; off < 256; off <<= 1) {
        float pA = 1.f, pB = 0.f;
        if (tid >= off) { pA = sA[tid - off]; pB = sB[tid - off]; }
        __syncthreads();
        if (tid >= off) {
            float cA = sA[tid], cB = sB[tid];
            sA[tid] = pA * cA;
            sB[tid] = fmaf(cA, pB, cB);
        }
        __syncthreads();
    }
    float eB = (tid > 0) ? sB[tid - 1] : 0.f;
    for (int j = 0; j < per; ++j) {
        int pidx = tid * per + j;
        int c = fwd ? pidx : (nch - 1 - pidx);
        hinit[(size_t)c * D + n] = eB;
        eB = fmaf(lA[j], eB, lB[j]);
    }
    if (out_final != nullptr && tid == 0) out_final[n] = sB[255];
}

__global__ __launch_bounds__(256) void scan_p2_kernel(
    const float* __restrict__ aggA, const float* __restrict__ aggB,
    float* __restrict__ hinit, float* __restrict__ out_final, int fwd, int nch)
{
    scan_body(aggA, aggB, hinit, out_final, fwd, nch, blockIdx.x, threadIdx.x);
}

__global__ __launch_bounds__(256) void scan_dual_kernel(
    const float* __restrict__ aggAf, const float* __restrict__ aggBf, float* __restrict__ hf,
    const float* __restrict__ aggAb, const float* __restrict__ aggBb, float* __restrict__ hb,
    int nch)
{
    int b = blockIdx.x;
    int fwd = (b < D) ? 1 : 0;
    int n = fwd ? b : (b - D);
    scan_body(fwd ? aggAf : aggAb, fwd ? aggBf : aggBb,
              fwd ? hf : hb, nullptr, fwd, nch, n, threadIdx.x);
}

// ---------------------------------------------------------------------------
extern "C" void kernel_launch(void* const* d_in, const int* in_sizes, int n_in,
                              void* d_out, int out_size, void* d_ws, size_t ws_size,
                              hipStream_t stream) {
    const float* story    = (const float*)d_in[0];
    const float* question = (const float*)d_in[1];
    const float* Wz_f = (const float*)d_in[2];
    const float* bz_f = (const float*)d_in[3];
    const float* Wh_f = (const float*)d_in[4];
    const float* bh_f = (const float*)d_in[5];
    const float* Wz_b = (const float*)d_in[6];
    const float* bz_b = (const float*)d_in[7];
    const float* Wh_b = (const float*)d_in[8];
    const float* bh_b = (const float*)d_in[9];

    const int T    = in_sizes[0] / D;            // 65536
    const int NCH  = T / BT;                     // 512
    const size_t TD = (size_t)T * D;
    const size_t WTE = 5 * 3 * 65536;

    // plan F: xb,q,xq (bf16) + wt + abf,abb (u32) + 4 agg arrays  (~231 MB)
    const size_t needF = 3 * TD * 2 + WTE * 2 + 2 * TD * 4
                       + (size_t)4 * NCH * D * 4 + 4096;
    const bool planF = ws_size >= needF;

    dim3 blk(256);
    dim3 gGrid((unsigned)(NCH * 4));             // 2048
    dim3 g2Grid((unsigned)(NCH * 8));            // 4096 (both dirs)
    dim3 pGrid((unsigned)(TD / 8 / 256));

    if (planF) {
        u16* xb = (u16*)d_ws;
        u16* q  = xb + TD;
        u16* xq = q  + TD;
        u16* wt = xq + TD;
        u32* abf = (u32*)(wt + WTE);
        u32* abb = abf + TD;
        float* aggAf = (float*)(abb + TD);
        float* aggBf = aggAf + (size_t)NCH * D;
        float* aggAb = aggBf + (size_t)NCH * D;
        float* aggBb = aggAb + (size_t)NCH * D;
        float* hinif = aggBf;                    // alias (safe)
        float* hinib = aggBb;                    // alias (safe)

        wtrans_kernel<<<dim3(5 * 3 * 65536 / 256), blk, 0, stream>>>(
            Wz_f, Wh_f, Wz_b, Wh_b, wt);
        prep0_kernel<<<pGrid, blk, 0, stream>>>(story, question, xb, q, xq);

        for (int l = 0; l < 3; ++l) {
            const u16*   wtf = wt + (size_t)l * 3 * 65536;
            const float* bzf = bz_f + (size_t)l * D;
            const float* bhf = bh_f + (size_t)l * D;

            if (l == 2) {
                qrn_g5<1,0><<<gGrid, blk, 0, stream>>>(
                    xb, q, xq, wtf, bzf, bhf, aggAf, aggBf, nullptr);
                scan_p2_kernel<<<dim3(D), blk, 0, stream>>>(
                    aggAf, aggBf, hinif, (float*)d_out, 1, NCH);
                break;
            }
            const u16*   wtb = wt + (size_t)(3 + l) * 3 * 65536;
            const float* bzb = bz_b + (size_t)l * D;
            const float* bhb = bh_b + (size_t)l * D;

            qrn_gboth<<<g2Grid, blk, 0, stream>>>(
                xb, q, xq, wtf, wtb, bzf, bhf, bzb, bhb,
                aggAf, aggBf, aggAb, aggBb, abf, abb);
            scan_dual_kernel<<<dim3(2 * D), blk, 0, stream>>>(
                aggAf, aggBf, hinif, aggAb, aggBb, hinib, NCH);
            replay_fb<<<gGrid, blk, 0, stream>>>(
                abf, abb, hinif, hinib, xb, q, xq);
        }
    } else {
        // ---------------- plan P fallback (R6, proven 683 us) ----------------
        u16* xb = (u16*)d_ws;
        u16* qA = xb + TD;
        u16* qB = qA + TD;
        u16* xq = qB + TD;
        u16* wt = xq + TD;
        u32*   ab   = (u32*)(wt + WTE);
        float* aggA = (float*)(ab + TD);
        float* aggB = aggA + (size_t)NCH * D;
        float* hini = aggB;

        wtrans_kernel<<<dim3(5 * 3 * 65536 / 256), blk, 0, stream>>>(
            Wz_f, Wh_f, Wz_b, Wh_b, wt);
        prep0_kernel<<<pGrid, blk, 0, stream>>>(story, question, xb, qA, xq);

        const u16* qcur  = qA;
        u16*       qnext = qB;

        for (int l = 0; l < 3; ++l) {
            const u16*   wtf = wt + (size_t)l * 3 * 65536;
            const float* bzf = bz_f + (size_t)l * D;
            const float* bhf = bh_f + (size_t)l * D;

            if (l == 2) {
                qrn_g5<1,0><<<gGrid, blk, 0, stream>>>(
                    xb, qcur, xq, wtf, bzf, bhf, aggA, aggB, nullptr);
                scan_p2_kernel<<<dim3(D), blk, 0, stream>>>(
                    aggA, aggB, hini, (float*)d_out, 1, NCH);
                break;
            }
            const u16*   wtb = wt + (size_t)(3 + l) * 3 * 65536;
            const float* bzb = bz_b + (size_t)l * D;
            const float* bhb = bh_b + (size_t)l * D;

            qrn_g5<1,1><<<gGrid, blk, 0, stream>>>(
                xb, qcur, xq, wtf, bzf, bhf, aggA, aggB, ab);
            scan_p2_kernel<<<dim3(D), blk, 0, stream>>>(aggA, aggB, hini, nullptr, 1, NCH);
            replay_f<<<gGrid, blk, 0, stream>>>(ab, hini, qnext);

            qrn_g5<0,1><<<gGrid, blk, 0, stream>>>(
                xb, qcur, xq, wtb, bzb, bhb, aggA, aggB, ab);
            scan_p2_kernel<<<dim3(D), blk, 0, stream>>>(aggA, aggB, hini, nullptr, 0, NCH);
            replay_b<<<gGrid, blk, 0, stream>>>(ab, hini, xb, qnext, xq);

            const u16* ts = qcur; qcur = qnext; qnext = (u16*)ts;
        }
    }
}